// Round 18
// baseline (51.957 us; speedup 1.0000x reference)
//
#include <hip/hip_runtime.h>
#include <hip/hip_bf16.h>
#include <cstddef>

// Pipeline (4 launches, early path):
//  kPrep2  : W split-transpose + enc single-pass (encT AND Ah/Al) + dec split
//  kMgemmC2: split-bf16 3-term MFMA GEMM (pure-copy staging); epilogue:
//            z=0 -> bf16 X1bf (halves kLogSm read traffic), z=1 -> f32 X2e
//  kLogSmB : pairwise-rcp logits from bf16 X1 + fused softmax ->
//            f32 attnw (output) + bf16 attnbf (for ctx GEMM)
//  kCtxMMB : MFMA batched context GEMM, pure-copy staging
// Fallback (ws < 18MB): r16-proven f32 path.

constexpr int nBt = 16, nSq = 128, nTq = 128, nEd = 512;

typedef __attribute__((ext_vector_type(4))) float f32x4;
typedef __attribute__((ext_vector_type(8))) short s16x8;

#define PRESCALE 2.8853900817779268f  /* 2*log2(e) */
#define LOG2E 1.4426950408889634f

__device__ __forceinline__ unsigned short to_bf(float f) {
    unsigned u = __builtin_bit_cast(unsigned, f);
    return (unsigned short)((u + 0x7FFFu + ((u >> 16) & 1u)) >> 16);  // RNE
}
__device__ __forceinline__ float from_bf(unsigned short h) {
    unsigned u = ((unsigned)h) << 16;
    return __builtin_bit_cast(float, u);
}

// n_a/A + n_b/B with ONE rcp: (n_a*B + n_b*A) * rcp(A*B)
__device__ __forceinline__ void pair_acc(
    float xa, float xb, float ca, float cb, float na, float nb, float& acc)
{
    const float A = fmaf(xa, ca, 1.0f);
    const float B = fmaf(xb, cb, 1.0f);
    const float r = __builtin_amdgcn_rcpf(A * B);
    float num = na * B;
    num = fmaf(nb, A, num);
    acc = fmaf(num, r, acc);
}

// ---- kPrep2: [0,512) W-split; [512,1536) enc tiles; [1536,2048) dec -----
__global__ __launch_bounds__(256) void kPrep2(
    const float* __restrict__ W1, const float* __restrict__ W2,
    unsigned short* __restrict__ WT,
    const float* __restrict__ enc, const float* __restrict__ dec,
    unsigned short* __restrict__ encT,
    unsigned short* __restrict__ Ah, unsigned short* __restrict__ Al)
{
    __shared__ float tl[32][33];
    const int r  = threadIdx.x >> 3;
    const int c4 = (threadIdx.x & 7) * 4;
    int bid = blockIdx.x;

    if (bid < 512) {   // W split-transpose (r8-proven)
        const int z = bid >> 8;
        const int yx = bid & 255;
        const int kB = (yx >> 4) * 32;
        const int nB = (yx & 15) * 32;
        const float* W = z ? W2 : W1;
        const float4 v = *(const float4*)&W[(size_t)(kB + r) * nEd + nB + c4];
        tl[r][c4 + 0] = v.x; tl[r][c4 + 1] = v.y;
        tl[r][c4 + 2] = v.z; tl[r][c4 + 3] = v.w;
        __syncthreads();
        unsigned short hh[4], ll[4];
        #pragma unroll
        for (int i = 0; i < 4; ++i) {
            const float x = tl[c4 + i][r];
            hh[i] = to_bf(x);
            ll[i] = to_bf(x - from_bf(hh[i]));
        }
        const size_t o = ((size_t)z * nEd + nB + r) * nEd + kB + c4;
        *(ushort4*)&WT[o] = *(ushort4*)hh;
        *(ushort4*)&WT[(size_t)2 * nEd * nEd + o] = *(ushort4*)ll;
    } else if (bid < 1536) {   // enc: one read -> encT AND Ah/Al (z=0 rows)
        bid -= 512;
        const int b = bid >> 6;
        const int r6 = bid & 63;
        const int eB = (r6 & 15) * 32;
        const int sB = (r6 >> 4) * 32;
        const size_t srcRow = (size_t)b * nSq + sB + r;
        const float4 v = *(const float4*)&enc[srcRow * nEd + eB + c4];
        if (Ah != nullptr) {   // row-major split planes (early path only)
            const float a4[4] = {v.x, v.y, v.z, v.w};
            unsigned short h[4], l[4];
            #pragma unroll
            for (int i = 0; i < 4; ++i) {
                h[i] = to_bf(a4[i]);
                l[i] = to_bf(a4[i] - from_bf(h[i]));
            }
            const size_t ao = srcRow * nEd + eB + c4;
            *(ushort4*)&Ah[ao] = *(ushort4*)h;
            *(ushort4*)&Al[ao] = *(ushort4*)l;
        }
        tl[r][c4 + 0] = v.x; tl[r][c4 + 1] = v.y;
        tl[r][c4 + 2] = v.z; tl[r][c4 + 3] = v.w;
        __syncthreads();
        unsigned short o[4];
        #pragma unroll
        for (int i = 0; i < 4; ++i) o[i] = to_bf(tl[c4 + i][r]);
        *(ushort4*)&encT[((size_t)b * nEd + eB + r) * nSq + sB + c4] = *(ushort4*)o;
    } else {   // dec streaming split (z=1 rows of Ah/Al)
        const size_t g0 = ((size_t)(bid - 1536) * 256 + threadIdx.x) * 8;
        const float4 a0 = *(const float4*)&dec[g0];
        const float4 a1 = *(const float4*)&dec[g0 + 4];
        const float a8[8] = {a0.x, a0.y, a0.z, a0.w, a1.x, a1.y, a1.z, a1.w};
        unsigned short h[8], l[8];
        #pragma unroll
        for (int i = 0; i < 8; ++i) {
            h[i] = to_bf(a8[i]);
            l[i] = to_bf(a8[i] - from_bf(h[i]));
        }
        const size_t ao = ((size_t)1 << 20) + g0;
        *(ushort4*)&Ah[ao]     = *(ushort4*)&h[0];
        *(ushort4*)&Ah[ao + 4] = *(ushort4*)&h[4];
        *(ushort4*)&Al[ao]     = *(ushort4*)&l[0];
        *(ushort4*)&Al[ao + 4] = *(ushort4*)&l[4];
    }
}

// ---- kMgemmC2: GEMM, pure-copy staging; z=0 -> bf16 X1bf, z=1 -> f32 ----
__global__ __launch_bounds__(256) void kMgemmC2(
    const unsigned short* __restrict__ Ah, const unsigned short* __restrict__ Al,
    const unsigned short* __restrict__ WT, const float* __restrict__ bias,
    unsigned short* __restrict__ X1bf, float* __restrict__ X2e)
{
    const int z = blockIdx.z;
    const unsigned short* __restrict__ Ahz = Ah + ((size_t)z << 20);
    const unsigned short* __restrict__ Alz = Al + ((size_t)z << 20);
    const unsigned short* __restrict__ Wh = WT + (size_t)z * nEd * nEd;
    const unsigned short* __restrict__ Wl = Wh + (size_t)2 * nEd * nEd;

    __shared__ unsigned short sAh[32][72];
    __shared__ unsigned short sAl[32][72];
    __shared__ unsigned short sBh[128][72];
    __shared__ unsigned short sBl[128][72];

    const int tid  = threadIdx.x;
    const int lane = tid & 63;
    const int wv   = tid >> 6;
    const int rowB = blockIdx.y * 32;
    const int colB = blockIdx.x * 128;

    const int ar8 = tid >> 3, ak8 = (tid & 7) * 8;
    const int br = tid >> 1, bc = (tid & 1) * 32;

    f32x4 acc[2][2] = {};
    const int l15 = lane & 15;
    const int kh  = lane >> 4;

    for (int k0 = 0; k0 < nEd; k0 += 64) {
        const size_t ao = (size_t)(rowB + ar8) * nEd + k0 + ak8;
        const s16x8 gah = *(const s16x8*)&Ahz[ao];
        const s16x8 gal = *(const s16x8*)&Alz[ao];
        const size_t wo = (size_t)(colB + br) * nEd + k0 + bc;
        s16x8 gh[4], gl[4];
        #pragma unroll
        for (int j = 0; j < 4; ++j) {
            gh[j] = *(const s16x8*)&Wh[wo + 8 * j];
            gl[j] = *(const s16x8*)&Wl[wo + 8 * j];
        }

        __syncthreads();
        *(s16x8*)&sAh[ar8][ak8] = gah;
        *(s16x8*)&sAl[ar8][ak8] = gal;
        #pragma unroll
        for (int j = 0; j < 4; ++j) {
            *(s16x8*)&sBh[br][bc + 8 * j] = gh[j];
            *(s16x8*)&sBl[br][bc + 8 * j] = gl[j];
        }
        __syncthreads();

        #pragma unroll
        for (int kk = 0; kk < 2; ++kk) {
            s16x8 fAh[2], fAl[2], fBh[2], fBl[2];
            #pragma unroll
            for (int mi = 0; mi < 2; ++mi) {
                fAh[mi] = *(const s16x8*)&sAh[mi * 16 + l15][kk * 32 + kh * 8];
                fAl[mi] = *(const s16x8*)&sAl[mi * 16 + l15][kk * 32 + kh * 8];
            }
            #pragma unroll
            for (int ni = 0; ni < 2; ++ni) {
                fBh[ni] = *(const s16x8*)&sBh[wv * 32 + ni * 16 + l15][kk * 32 + kh * 8];
                fBl[ni] = *(const s16x8*)&sBl[wv * 32 + ni * 16 + l15][kk * 32 + kh * 8];
            }
            #pragma unroll
            for (int mi = 0; mi < 2; ++mi)
                #pragma unroll
                for (int ni = 0; ni < 2; ++ni) {
                    f32x4 a = acc[mi][ni];
                    a = __builtin_amdgcn_mfma_f32_16x16x32_bf16(fAh[mi], fBh[ni], a, 0, 0, 0);
                    a = __builtin_amdgcn_mfma_f32_16x16x32_bf16(fAl[mi], fBh[ni], a, 0, 0, 0);
                    a = __builtin_amdgcn_mfma_f32_16x16x32_bf16(fAh[mi], fBl[ni], a, 0, 0, 0);
                    acc[mi][ni] = a;
                }
        }
    }

    #pragma unroll
    for (int ni = 0; ni < 2; ++ni) {
        const int col = colB + wv * 32 + ni * 16 + l15;
        const float bval = z ? bias[col] : 0.0f;
        #pragma unroll
        for (int mi = 0; mi < 2; ++mi) {
            #pragma unroll
            for (int r = 0; r < 4; ++r) {
                const int row = rowB + mi * 16 + kh * 4 + r;
                const float e = __builtin_amdgcn_exp2f((acc[mi][ni][r] + bval) * PRESCALE);
                if (z == 0)
                    X1bf[(size_t)row * nEd + col] = to_bf(e);
                else
                    X2e[(size_t)row * nEd + col] = e;
            }
        }
    }
}

// ---- kLogSmB: pairwise-rcp logits (bf16 X1) + fused softmax -------------
// Grid (T/2=64, B=16), 4 waves. Wave w covers s in [w*32, +32) for t-pair.
__global__ __launch_bounds__(256) void kLogSmB(
    const unsigned short* __restrict__ X1bf,  // [B*S,E] bf16 exp2'd
    const float* __restrict__ X2e,            // [B*T,E] f32 exp2'd
    const float* __restrict__ V,              // [E]
    float* __restrict__ attnw,                // [B*T,S] f32 weights (output)
    unsigned short* __restrict__ attnbf)      // [B*T,S] bf16 weights
{
    const int tg = blockIdx.x, b = blockIdx.y;
    const int tid  = threadIdx.x;
    const int lane = tid & 63;
    const int w    = tid >> 6;
    const int s0 = w * 32;
    const int t0 = tg * 2;

    __shared__ float sm[2][nSq];

    const float4* vp = (const float4*)V;
    float4 n0 = vp[lane * 2], n1 = vp[lane * 2 + 1];
    n0.x *= -2.f; n0.y *= -2.f; n0.z *= -2.f; n0.w *= -2.f;
    n1.x *= -2.f; n1.y *= -2.f; n1.z *= -2.f; n1.w *= -2.f;

    float4 c0[2], c1[2];
    #pragma unroll
    for (int i = 0; i < 2; ++i) {
        const float4* xp = (const float4*)(X2e + ((size_t)b * nTq + t0 + i) * nEd);
        c0[i] = xp[lane * 2];
        c1[i] = xp[lane * 2 + 1];
    }

    const unsigned short* X1b = X1bf + (size_t)b * nSq * nEd;
    s16x8 xraw = *(const s16x8*)&X1b[(size_t)s0 * nEd + lane * 8];

    #pragma unroll 4
    for (int si = 0; si < 32; ++si) {
        const s16x8 cur = xraw;
        if (si < 31)
            xraw = *(const s16x8*)&X1b[(size_t)(s0 + si + 1) * nEd + lane * 8];
        float cx[8];
        #pragma unroll
        for (int i = 0; i < 8; ++i)
            cx[i] = from_bf((unsigned short)cur[i]);

        float a0 = 0.f, a1 = 0.f;
        pair_acc(cx[0], cx[1], c0[0].x, c0[0].y, n0.x, n0.y, a0);
        pair_acc(cx[2], cx[3], c0[0].z, c0[0].w, n0.z, n0.w, a0);
        pair_acc(cx[4], cx[5], c1[0].x, c1[0].y, n1.x, n1.y, a0);
        pair_acc(cx[6], cx[7], c1[0].z, c1[0].w, n1.z, n1.w, a0);
        pair_acc(cx[0], cx[1], c0[1].x, c0[1].y, n0.x, n0.y, a1);
        pair_acc(cx[2], cx[3], c0[1].z, c0[1].w, n0.z, n0.w, a1);
        pair_acc(cx[4], cx[5], c1[1].x, c1[1].y, n1.x, n1.y, a1);
        pair_acc(cx[6], cx[7], c1[1].z, c1[1].w, n1.z, n1.w, a1);

        const float p0 = a0 + __shfl_xor(a0, 1);
        const float p1 = a1 + __shfl_xor(a1, 1);
        float q = (lane & 1) ? p1 : p0;
        q += __shfl_xor(q, 2);
        q += __shfl_xor(q, 4);
        q += __shfl_xor(q, 8);
        q += __shfl_xor(q, 16);
        q += __shfl_xor(q, 32);
        if (lane < 2) sm[lane][s0 + si] = q;
    }
    __syncthreads();

    if (w < 2) {
        const float l0 = sm[w][lane], l1 = sm[w][lane + 64];
        float m = fmaxf(l0, l1);
        #pragma unroll
        for (int off = 32; off >= 1; off >>= 1)
            m = fmaxf(m, __shfl_xor(m, off));
        const float e0 = __builtin_amdgcn_exp2f((l0 - m) * LOG2E);
        const float e1 = __builtin_amdgcn_exp2f((l1 - m) * LOG2E);
        float sum = e0 + e1;
        #pragma unroll
        for (int off = 32; off >= 1; off >>= 1)
            sum += __shfl_xor(sum, off);
        const float inv = __builtin_amdgcn_rcpf(sum);
        const float w0 = e0 * inv, w1 = e1 * inv;
        const size_t ro = ((size_t)b * nTq + t0 + w) * nSq;
        attnw[ro + lane]      = w0;
        attnw[ro + lane + 64] = w1;
        attnbf[ro + lane]      = to_bf(w0);
        attnbf[ro + lane + 64] = to_bf(w1);
    }
}

// ---- kCtxMMB: ctx[b] = attnbf[b] @ encT[b]^T, pure-copy staging ---------
__global__ __launch_bounds__(256) void kCtxMMB(
    const unsigned short* __restrict__ attnbf,  // [B*T,S] bf16 weights
    const unsigned short* __restrict__ encT,    // [B*E,S]
    float* __restrict__ ctx)                    // [B*T,E]
{
    const int b  = blockIdx.z;
    const int tB = blockIdx.y * 32;
    const int eB = blockIdx.x * 64;

    __shared__ unsigned short sA[32][136];
    __shared__ unsigned short sB[64][136];

    const int tid  = threadIdx.x;
    const int lane = tid & 63;
    const int w    = tid >> 6;
    const int wm = (w >> 1) * 16;
    const int wn = (w & 1) * 32;
    const int l15 = lane & 15;
    const int kh  = lane >> 4;

    {
        const int r = tid >> 3, c = (tid & 7) * 16;
        const size_t o = ((size_t)b * nTq + tB + r) * nSq + c;
        *(s16x8*)&sA[r][c]     = *(const s16x8*)&attnbf[o];
        *(s16x8*)&sA[r][c + 8] = *(const s16x8*)&attnbf[o + 8];
    }
    {
        const int r = tid >> 2, c = (tid & 3) * 32;
        const size_t o = ((size_t)b * nEd + eB + r) * nSq + c;
        *(s16x8*)&sB[r][c]      = *(const s16x8*)&encT[o];
        *(s16x8*)&sB[r][c + 8]  = *(const s16x8*)&encT[o + 8];
        *(s16x8*)&sB[r][c + 16] = *(const s16x8*)&encT[o + 16];
        *(s16x8*)&sB[r][c + 24] = *(const s16x8*)&encT[o + 24];
    }
    __syncthreads();

    f32x4 acc[2] = {};
    #pragma unroll
    for (int kk = 0; kk < 4; ++kk) {
        const s16x8 fA = *(const s16x8*)&sA[wm + l15][kk * 32 + kh * 8];
        #pragma unroll
        for (int ni = 0; ni < 2; ++ni) {
            const s16x8 fB = *(const s16x8*)&sB[wn + ni * 16 + l15][kk * 32 + kh * 8];
            acc[ni] = __builtin_amdgcn_mfma_f32_16x16x32_bf16(fA, fB, acc[ni], 0, 0, 0);
        }
    }

    #pragma unroll
    for (int ni = 0; ni < 2; ++ni) {
        const int e = eB + wn + ni * 16 + l15;
        #pragma unroll
        for (int r = 0; r < 4; ++r) {
            const int t = tB + wm + kh * 4 + r;
            ctx[((size_t)b * nTq + t) * nEd + e] = acc[ni][r];
        }
    }
}

// ======================= fallback (r16-proven) ===========================
__global__ __launch_bounds__(256) void kMgemmB(
    const float* __restrict__ A0, const float* __restrict__ A1,
    const unsigned short* __restrict__ WT, const float* __restrict__ bias,
    float* __restrict__ C0, float* __restrict__ C1)
{
    const int z = blockIdx.z;
    const float* __restrict__ A = z ? A1 : A0;
    const unsigned short* __restrict__ Wh = WT + (size_t)z * nEd * nEd;
    const unsigned short* __restrict__ Wl = Wh + (size_t)2 * nEd * nEd;
    float* __restrict__ C = z ? C1 : C0;

    __shared__ unsigned short sAh[32][72];
    __shared__ unsigned short sAl[32][72];
    __shared__ unsigned short sBh[128][72];
    __shared__ unsigned short sBl[128][72];

    const int tid  = threadIdx.x;
    const int lane = tid & 63;
    const int wv   = tid >> 6;
    const int rowB = blockIdx.y * 32;
    const int colB = blockIdx.x * 128;
    const int ar = tid >> 3, ak = (tid & 7) * 8;
    const int br = tid >> 1, bc = (tid & 1) * 32;
    f32x4 acc[2][2] = {};
    const int l15 = lane & 15;
    const int kh  = lane >> 4;

    for (int k0 = 0; k0 < nEd; k0 += 64) {
        const float4 ga0 = *(const float4*)&A[(size_t)(rowB + ar) * nEd + k0 + ak];
        const float4 ga1 = *(const float4*)&A[(size_t)(rowB + ar) * nEd + k0 + ak + 4];
        const size_t wo = (size_t)(colB + br) * nEd + k0 + bc;
        s16x8 gh[4], gl[4];
        #pragma unroll
        for (int j = 0; j < 4; ++j) {
            gh[j] = *(const s16x8*)&Wh[wo + 8 * j];
            gl[j] = *(const s16x8*)&Wl[wo + 8 * j];
        }
        __syncthreads();
        {
            const float a8[8] = {ga0.x, ga0.y, ga0.z, ga0.w,
                                 ga1.x, ga1.y, ga1.z, ga1.w};
            unsigned short h[8], l[8];
            #pragma unroll
            for (int i = 0; i < 8; ++i) {
                h[i] = to_bf(a8[i]);
                l[i] = to_bf(a8[i] - from_bf(h[i]));
            }
            *(ushort4*)&sAh[ar][ak]     = *(ushort4*)&h[0];
            *(ushort4*)&sAh[ar][ak + 4] = *(ushort4*)&h[4];
            *(ushort4*)&sAl[ar][ak]     = *(ushort4*)&l[0];
            *(ushort4*)&sAl[ar][ak + 4] = *(ushort4*)&l[4];
        }
        #pragma unroll
        for (int j = 0; j < 4; ++j) {
            *(s16x8*)&sBh[br][bc + 8 * j] = gh[j];
            *(s16x8*)&sBl[br][bc + 8 * j] = gl[j];
        }
        __syncthreads();
        #pragma unroll
        for (int kk = 0; kk < 2; ++kk) {
            s16x8 fAh[2], fAl[2], fBh[2], fBl[2];
            #pragma unroll
            for (int mi = 0; mi < 2; ++mi) {
                fAh[mi] = *(const s16x8*)&sAh[mi * 16 + l15][kk * 32 + kh * 8];
                fAl[mi] = *(const s16x8*)&sAl[mi * 16 + l15][kk * 32 + kh * 8];
            }
            #pragma unroll
            for (int ni = 0; ni < 2; ++ni) {
                fBh[ni] = *(const s16x8*)&sBh[wv * 32 + ni * 16 + l15][kk * 32 + kh * 8];
                fBl[ni] = *(const s16x8*)&sBl[wv * 32 + ni * 16 + l15][kk * 32 + kh * 8];
            }
            #pragma unroll
            for (int mi = 0; mi < 2; ++mi)
                #pragma unroll
                for (int ni = 0; ni < 2; ++ni) {
                    f32x4 a = acc[mi][ni];
                    a = __builtin_amdgcn_mfma_f32_16x16x32_bf16(fAh[mi], fBh[ni], a, 0, 0, 0);
                    a = __builtin_amdgcn_mfma_f32_16x16x32_bf16(fAl[mi], fBh[ni], a, 0, 0, 0);
                    a = __builtin_amdgcn_mfma_f32_16x16x32_bf16(fAh[mi], fBl[ni], a, 0, 0, 0);
                    acc[mi][ni] = a;
                }
        }
    }
    #pragma unroll
    for (int ni = 0; ni < 2; ++ni) {
        const int col = colB + wv * 32 + ni * 16 + l15;
        const float bval = z ? bias[col] : 0.0f;
        #pragma unroll
        for (int mi = 0; mi < 2; ++mi) {
            #pragma unroll
            for (int r = 0; r < 4; ++r) {
                const int row = rowB + mi * 16 + kh * 4 + r;
                C[(size_t)row * nEd + col] =
                    __builtin_amdgcn_exp2f((acc[mi][ni][r] + bval) * PRESCALE);
            }
        }
    }
}

__global__ __launch_bounds__(256) void kLogSmF(
    const float* __restrict__ X1e, const float* __restrict__ X2e,
    const float* __restrict__ V, float* __restrict__ attnw)
{
    const int tg = blockIdx.x, b = blockIdx.y;
    const int tid  = threadIdx.x;
    const int lane = tid & 63;
    const int w    = tid >> 6;
    const int s0 = w * 32;
    const int t0 = tg * 2;
    __shared__ float sm[2][nSq];

    const float4* vp = (const float4*)V;
    float4 n0 = vp[lane * 2], n1 = vp[lane * 2 + 1];
    n0.x *= -2.f; n0.y *= -2.f; n0.z *= -2.f; n0.w *= -2.f;
    n1.x *= -2.f; n1.y *= -2.f; n1.z *= -2.f; n1.w *= -2.f;
    float4 c0[2], c1[2];
    #pragma unroll
    for (int i = 0; i < 2; ++i) {
        const float4* xp = (const float4*)(X2e + ((size_t)b * nTq + t0 + i) * nEd);
        c0[i] = xp[lane * 2];
        c1[i] = xp[lane * 2 + 1];
    }
    const float* X1b = X1e + (size_t)b * nSq * nEd;
    float4 x0 = ((const float4*)(X1b + (size_t)s0 * nEd))[lane * 2];
    float4 x1 = ((const float4*)(X1b + (size_t)s0 * nEd))[lane * 2 + 1];
    #pragma unroll 4
    for (int si = 0; si < 32; ++si) {
        const float4 cx0 = x0, cx1 = x1;
        if (si < 31) {
            const float4* np = (const float4*)(X1b + (size_t)(s0 + si + 1) * nEd);
            x0 = np[lane * 2];
            x1 = np[lane * 2 + 1];
        }
        float a0 = 0.f, a1 = 0.f;
        pair_acc(cx0.x, cx0.y, c0[0].x, c0[0].y, n0.x, n0.y, a0);
        pair_acc(cx0.z, cx0.w, c0[0].z, c0[0].w, n0.z, n0.w, a0);
        pair_acc(cx1.x, cx1.y, c1[0].x, c1[0].y, n1.x, n1.y, a0);
        pair_acc(cx1.z, cx1.w, c1[0].z, c1[0].w, n1.z, n1.w, a0);
        pair_acc(cx0.x, cx0.y, c0[1].x, c0[1].y, n0.x, n0.y, a1);
        pair_acc(cx0.z, cx0.w, c0[1].z, c0[1].w, n0.z, n0.w, a1);
        pair_acc(cx1.x, cx1.y, c1[1].x, c1[1].y, n1.x, n1.y, a1);
        pair_acc(cx1.z, cx1.w, c1[1].z, c1[1].w, n1.z, n1.w, a1);
        const float p0 = a0 + __shfl_xor(a0, 1);
        const float p1 = a1 + __shfl_xor(a1, 1);
        float q = (lane & 1) ? p1 : p0;
        q += __shfl_xor(q, 2);
        q += __shfl_xor(q, 4);
        q += __shfl_xor(q, 8);
        q += __shfl_xor(q, 16);
        q += __shfl_xor(q, 32);
        if (lane < 2) sm[lane][s0 + si] = q;
    }
    __syncthreads();
    if (w < 2) {
        const float l0 = sm[w][lane], l1 = sm[w][lane + 64];
        float m = fmaxf(l0, l1);
        #pragma unroll
        for (int off = 32; off >= 1; off >>= 1)
            m = fmaxf(m, __shfl_xor(m, off));
        const float e0 = __builtin_amdgcn_exp2f((l0 - m) * LOG2E);
        const float e1 = __builtin_amdgcn_exp2f((l1 - m) * LOG2E);
        float sum = e0 + e1;
        #pragma unroll
        for (int off = 32; off >= 1; off >>= 1)
            sum += __shfl_xor(sum, off);
        const float inv = __builtin_amdgcn_rcpf(sum);
        float* ap = attnw + ((size_t)b * nTq + t0 + w) * nSq;
        ap[lane]      = e0 * inv;
        ap[lane + 64] = e1 * inv;
    }
}

__global__ __launch_bounds__(256) void kEncT(
    const float* __restrict__ enc, unsigned short* __restrict__ encT)
{
    const int b = blockIdx.z;
    __shared__ float tl[32][33];
    const int r  = threadIdx.x >> 3;
    const int c4 = (threadIdx.x & 7) * 4;
    const int sB = blockIdx.y * 32;
    const int eB = blockIdx.x * 32;
    const float4 v = *(const float4*)&enc[((size_t)b * nSq + sB + r) * nEd + eB + c4];
    tl[r][c4 + 0] = v.x; tl[r][c4 + 1] = v.y;
    tl[r][c4 + 2] = v.z; tl[r][c4 + 3] = v.w;
    __syncthreads();
    unsigned short o[4];
    #pragma unroll
    for (int i = 0; i < 4; ++i) o[i] = to_bf(tl[c4 + i][r]);
    *(ushort4*)&encT[((size_t)b * nEd + eB + r) * nSq + sB + c4] = *(ushort4*)o;
}

__global__ __launch_bounds__(256) void kCtxMMF(
    const float* __restrict__ attnw, const unsigned short* __restrict__ encT,
    float* __restrict__ ctx)
{
    const int b  = blockIdx.z;
    const int tB = blockIdx.y * 32;
    const int eB = blockIdx.x * 64;
    __shared__ unsigned short sA[32][136];
    __shared__ unsigned short sB[64][136];
    const int tid  = threadIdx.x;
    const int lane = tid & 63;
    const int w    = tid >> 6;
    const int wm = (w >> 1) * 16;
    const int wn = (w & 1) * 32;
    const int l15 = lane & 15;
    const int kh  = lane >> 4;
    {
        const int r = tid >> 3, c = (tid & 7) * 16;
        const float* ap = &attnw[((size_t)b * nTq + tB + r) * nSq + c];
        unsigned short h[16];
        #pragma unroll
        for (int q = 0; q < 4; ++q) {
            const float4 v = *(const float4*)(ap + 4 * q);
            h[4 * q + 0] = to_bf(v.x); h[4 * q + 1] = to_bf(v.y);
            h[4 * q + 2] = to_bf(v.z); h[4 * q + 3] = to_bf(v.w);
        }
        *(s16x8*)&sA[r][c]     = *(s16x8*)&h[0];
        *(s16x8*)&sA[r][c + 8] = *(s16x8*)&h[8];
    }
    {
        const int r = tid >> 2, c = (tid & 3) * 32;
        const size_t o = ((size_t)b * nEd + eB + r) * nSq + c;
        *(s16x8*)&sB[r][c]      = *(const s16x8*)&encT[o];
        *(s16x8*)&sB[r][c + 8]  = *(const s16x8*)&encT[o + 8];
        *(s16x8*)&sB[r][c + 16] = *(const s16x8*)&encT[o + 16];
        *(s16x8*)&sB[r][c + 24] = *(const s16x8*)&encT[o + 24];
    }
    __syncthreads();
    f32x4 acc[2] = {};
    #pragma unroll
    for (int kk = 0; kk < 4; ++kk) {
        const s16x8 fA = *(const s16x8*)&sA[wm + l15][kk * 32 + kh * 8];
        #pragma unroll
        for (int ni = 0; ni < 2; ++ni) {
            const s16x8 fB = *(const s16x8*)&sB[wn + ni * 16 + l15][kk * 32 + kh * 8];
            acc[ni] = __builtin_amdgcn_mfma_f32_16x16x32_bf16(fA, fB, acc[ni], 0, 0, 0);
        }
    }
    #pragma unroll
    for (int ni = 0; ni < 2; ++ni) {
        const int e = eB + wn + ni * 16 + l15;
        #pragma unroll
        for (int r = 0; r < 4; ++r) {
            const int t = tB + wm + kh * 4 + r;
            ctx[((size_t)b * nTq + t) * nEd + e] = acc[ni][r];
        }
    }
}

extern "C" void kernel_launch(void* const* d_in, const int* in_sizes, int n_in,
                              void* d_out, int out_size, void* d_ws, size_t ws_size,
                              hipStream_t stream) {
    const float* enc = (const float*)d_in[0];   // [16,128,512]
    const float* dec = (const float*)d_in[1];   // [16,128,512]
    const float* W1  = (const float*)d_in[2];   // [512,512]
    const float* W2  = (const float*)d_in[3];   // [512,512]
    const float* bv  = (const float*)d_in[4];   // [512]
    const float* V   = (const float*)d_in[5];   // [512]

    float* ctx   = (float*)d_out;                           // [16,128,512] 4MB
    float* attnw = (float*)d_out + (size_t)nBt * nTq * nEd; // [16,128,128] 1MB

    // WT (4MB hi+lo) in d_out ctx region — dead before ctx is written.
    unsigned short* WT = (unsigned short*)d_out;

    const size_t MB = (size_t)1024 * 1024;
    const bool early = ws_size >= 18 * MB + 4096;

    if (early) {
        unsigned short* X1bf   = (unsigned short*)d_ws;                 // 2MB
        unsigned short* attnbf = (unsigned short*)((char*)d_ws + 2*MB); // 512KB
        float*          X2e    = (float*)((char*)d_ws + 4 * MB);        // 4MB
        unsigned short* encT   = (unsigned short*)((char*)d_ws + 8*MB); // 2MB
        unsigned short* Ah     = (unsigned short*)((char*)d_ws + 10*MB);// 4MB
        unsigned short* Al     = (unsigned short*)((char*)d_ws + 14*MB);// 4MB

        kPrep2<<<dim3(2048), dim3(256), 0, stream>>>(
            W1, W2, WT, enc, dec, encT, Ah, Al);
        kMgemmC2<<<dim3(nEd / 128, (nBt * nSq) / 32, 2), dim3(256), 0, stream>>>(
            Ah, Al, WT, bv, X1bf, X2e);
        kLogSmB<<<dim3(nTq / 2, nBt), dim3(256), 0, stream>>>(
            X1bf, X2e, V, attnw, attnbf);
        kCtxMMB<<<dim3(nEd / 64, nTq / 32, nBt), dim3(256), 0, stream>>>(
            attnbf, encT, ctx);
    } else {
        float* ws0 = (float*)d_ws;                    // f32 X1e, 4MB
        float* ws1 = ws0 + (size_t)nBt * nSq * nEd;   // f32 X2e, 4MB
        unsigned short* encT = (unsigned short*)d_ws; // reuses X1e after kLogSmF

        kPrep2<<<dim3(512), dim3(256), 0, stream>>>(
            W1, W2, WT, enc, dec, nullptr, nullptr, nullptr);
        kMgemmB<<<dim3(nEd / 128, (nBt * nSq) / 32, 2), dim3(256), 0, stream>>>(
            enc, dec, WT, bv, ws0, ws1);
        kLogSmF<<<dim3(nTq / 2, nBt), dim3(256), 0, stream>>>(ws0, ws1, V, attnw);
        kEncT<<<dim3(nEd / 32, nSq / 32, nBt), dim3(256), 0, stream>>>(enc, encT);
        kCtxMMF<<<dim3(nEd / 64, nTq / 32, nBt), dim3(256), 0, stream>>>(
            attnw, encT, ctx);
    }
}

// Round 20
// 50.424 us; speedup vs baseline: 1.0304x; 1.0304x over previous
//
#include <hip/hip_runtime.h>
#include <hip/hip_bf16.h>
#include <cstddef>

// Pipeline (4 launches, early path):
//  kPrep   : W split-transpose + encT transpose + A(enc,dec) split-bf16
//            pre-pass (hoists ~80 VALU/iter out of the GEMM hot loop)
//  kMgemmC : split-bf16 3-term MFMA GEMM, 32x128 tile, staging = PURE
//            s16x8 copies (no conversion VALU); epilogue stores exp2
//  kLogSm  : pairwise-rcp logits + fused softmax (r16-proven)
//  kCtxMM  : MFMA batched context GEMM (r13-proven)
// Fallback (ws too small): r16 path with in-loop split (kMgemmB).
//
// NOTE (r19 lesson): a 512-thread 4-t kLogSm variant was ~2.7us faster but
// diverged across graph replays (post-timing absmax 9.1e-2). Reverted to this
// r17 configuration — fastest build that passes re-validation.

constexpr int nBt = 16, nSq = 128, nTq = 128, nEd = 512;

typedef __attribute__((ext_vector_type(4))) float f32x4;
typedef __attribute__((ext_vector_type(8))) short s16x8;

#define PRESCALE 2.8853900817779268f  /* 2*log2(e) */
#define LOG2E 1.4426950408889634f

__device__ __forceinline__ unsigned short to_bf(float f) {
    unsigned u = __builtin_bit_cast(unsigned, f);
    return (unsigned short)((u + 0x7FFFu + ((u >> 16) & 1u)) >> 16);  // RNE
}
__device__ __forceinline__ float from_bf(unsigned short h) {
    unsigned u = ((unsigned)h) << 16;
    return __builtin_bit_cast(float, u);
}

// n_a/A + n_b/B with ONE rcp: (n_a*B + n_b*A) * rcp(A*B)
__device__ __forceinline__ void pair_acc(
    float xa, float xb, float ca, float cb, float na, float nb, float& acc)
{
    const float A = fmaf(xa, ca, 1.0f);
    const float B = fmaf(xb, cb, 1.0f);
    const float r = __builtin_amdgcn_rcpf(A * B);
    float num = na * B;
    num = fmaf(nb, A, num);
    acc = fmaf(num, r, acc);
}

// ---- kPrep: [0,512) W-split; [512,1536) encT; [1536,2560) A-split -------
__global__ __launch_bounds__(256) void kPrep(
    const float* __restrict__ W1, const float* __restrict__ W2,
    unsigned short* __restrict__ WT,
    const float* __restrict__ enc, const float* __restrict__ dec,
    unsigned short* __restrict__ encT,
    unsigned short* __restrict__ Ah, unsigned short* __restrict__ Al)
{
    __shared__ float tl[32][33];
    const int r  = threadIdx.x >> 3;
    const int c4 = (threadIdx.x & 7) * 4;
    int bid = blockIdx.x;

    if (bid < 512) {   // W split-transpose (r8-proven)
        const int z = bid >> 8;
        const int yx = bid & 255;
        const int kB = (yx >> 4) * 32;
        const int nB = (yx & 15) * 32;
        const float* W = z ? W2 : W1;
        const float4 v = *(const float4*)&W[(size_t)(kB + r) * nEd + nB + c4];
        tl[r][c4 + 0] = v.x; tl[r][c4 + 1] = v.y;
        tl[r][c4 + 2] = v.z; tl[r][c4 + 3] = v.w;
        __syncthreads();
        unsigned short hh[4], ll[4];
        #pragma unroll
        for (int i = 0; i < 4; ++i) {
            const float x = tl[c4 + i][r];
            hh[i] = to_bf(x);
            ll[i] = to_bf(x - from_bf(hh[i]));
        }
        const size_t o = ((size_t)z * nEd + nB + r) * nEd + kB + c4;
        *(ushort4*)&WT[o] = *(ushort4*)hh;
        *(ushort4*)&WT[(size_t)2 * nEd * nEd + o] = *(ushort4*)ll;
    } else if (bid < 1536) {   // encT transpose (r9-proven)
        bid -= 512;
        const int b = bid >> 6;
        const int r6 = bid & 63;
        const int eB = (r6 & 15) * 32;
        const int sB = (r6 >> 4) * 32;
        const float4 v = *(const float4*)&enc[((size_t)b * nSq + sB + r) * nEd + eB + c4];
        tl[r][c4 + 0] = v.x; tl[r][c4 + 1] = v.y;
        tl[r][c4 + 2] = v.z; tl[r][c4 + 3] = v.w;
        __syncthreads();
        unsigned short o[4];
        #pragma unroll
        for (int i = 0; i < 4; ++i) o[i] = to_bf(tl[c4 + i][r]);
        *(ushort4*)&encT[((size_t)b * nEd + eB + r) * nSq + sB + c4] = *(ushort4*)o;
    } else {   // A split pre-pass (streaming, no transpose)
        const size_t g0 = ((size_t)(bid - 1536) * 256 + threadIdx.x) * 8;
        const int z = (int)(g0 >> 20);            // 2048*512 = 2^20 per z
        const size_t rem = g0 & 0xFFFFFu;
        const float* A = z ? dec : enc;
        const float4 a0 = *(const float4*)&A[rem];
        const float4 a1 = *(const float4*)&A[rem + 4];
        const float a8[8] = {a0.x, a0.y, a0.z, a0.w, a1.x, a1.y, a1.z, a1.w};
        unsigned short h[8], l[8];
        #pragma unroll
        for (int i = 0; i < 8; ++i) {
            h[i] = to_bf(a8[i]);
            l[i] = to_bf(a8[i] - from_bf(h[i]));
        }
        *(ushort4*)&Ah[g0]     = *(ushort4*)&h[0];
        *(ushort4*)&Ah[g0 + 4] = *(ushort4*)&h[4];
        *(ushort4*)&Al[g0]     = *(ushort4*)&l[0];
        *(ushort4*)&Al[g0 + 4] = *(ushort4*)&l[4];
    }
}

// ---- kMgemmC: exp2((A @ W [+bias]) * PS); staging = pure copies ---------
__global__ __launch_bounds__(256) void kMgemmC(
    const unsigned short* __restrict__ Ah, const unsigned short* __restrict__ Al,
    const unsigned short* __restrict__ WT, const float* __restrict__ bias,
    float* __restrict__ C0, float* __restrict__ C1)
{
    const int z = blockIdx.z;
    const unsigned short* __restrict__ Ahz = Ah + ((size_t)z << 20);
    const unsigned short* __restrict__ Alz = Al + ((size_t)z << 20);
    const unsigned short* __restrict__ Wh = WT + (size_t)z * nEd * nEd;
    const unsigned short* __restrict__ Wl = Wh + (size_t)2 * nEd * nEd;
    float* __restrict__ C = z ? C1 : C0;

    __shared__ unsigned short sAh[32][72];
    __shared__ unsigned short sAl[32][72];
    __shared__ unsigned short sBh[128][72];
    __shared__ unsigned short sBl[128][72];

    const int tid  = threadIdx.x;
    const int lane = tid & 63;
    const int wv   = tid >> 6;
    const int rowB = blockIdx.y * 32;
    const int colB = blockIdx.x * 128;

    const int ar = tid >> 3, ak = (tid & 3) * 8;    // note: tid&7 gives 8 slots,
    // but A-tile is 32x64 = 2048 elems/plane = 8/thread: ar in [0,32), ak via (tid&7)*8
    const int ar8 = tid >> 3, ak8 = (tid & 7) * 8;
    const int br = tid >> 1, bc = (tid & 1) * 32;

    f32x4 acc[2][2] = {};
    const int l15 = lane & 15;
    const int kh  = lane >> 4;

    for (int k0 = 0; k0 < nEd; k0 += 64) {
        const size_t ao = (size_t)(rowB + ar8) * nEd + k0 + ak8;
        const s16x8 gah = *(const s16x8*)&Ahz[ao];
        const s16x8 gal = *(const s16x8*)&Alz[ao];
        const size_t wo = (size_t)(colB + br) * nEd + k0 + bc;
        s16x8 gh[4], gl[4];
        #pragma unroll
        for (int j = 0; j < 4; ++j) {
            gh[j] = *(const s16x8*)&Wh[wo + 8 * j];
            gl[j] = *(const s16x8*)&Wl[wo + 8 * j];
        }

        __syncthreads();
        *(s16x8*)&sAh[ar8][ak8] = gah;
        *(s16x8*)&sAl[ar8][ak8] = gal;
        #pragma unroll
        for (int j = 0; j < 4; ++j) {
            *(s16x8*)&sBh[br][bc + 8 * j] = gh[j];
            *(s16x8*)&sBl[br][bc + 8 * j] = gl[j];
        }
        __syncthreads();

        #pragma unroll
        for (int kk = 0; kk < 2; ++kk) {
            s16x8 fAh[2], fAl[2], fBh[2], fBl[2];
            #pragma unroll
            for (int mi = 0; mi < 2; ++mi) {
                fAh[mi] = *(const s16x8*)&sAh[mi * 16 + l15][kk * 32 + kh * 8];
                fAl[mi] = *(const s16x8*)&sAl[mi * 16 + l15][kk * 32 + kh * 8];
            }
            #pragma unroll
            for (int ni = 0; ni < 2; ++ni) {
                fBh[ni] = *(const s16x8*)&sBh[wv * 32 + ni * 16 + l15][kk * 32 + kh * 8];
                fBl[ni] = *(const s16x8*)&sBl[wv * 32 + ni * 16 + l15][kk * 32 + kh * 8];
            }
            #pragma unroll
            for (int mi = 0; mi < 2; ++mi)
                #pragma unroll
                for (int ni = 0; ni < 2; ++ni) {
                    f32x4 a = acc[mi][ni];
                    a = __builtin_amdgcn_mfma_f32_16x16x32_bf16(fAh[mi], fBh[ni], a, 0, 0, 0);
                    a = __builtin_amdgcn_mfma_f32_16x16x32_bf16(fAl[mi], fBh[ni], a, 0, 0, 0);
                    a = __builtin_amdgcn_mfma_f32_16x16x32_bf16(fAh[mi], fBl[ni], a, 0, 0, 0);
                    acc[mi][ni] = a;
                }
        }
    }

    #pragma unroll
    for (int ni = 0; ni < 2; ++ni) {
        const int col = colB + wv * 32 + ni * 16 + l15;
        const float bval = z ? bias[col] : 0.0f;
        #pragma unroll
        for (int mi = 0; mi < 2; ++mi) {
            #pragma unroll
            for (int r = 0; r < 4; ++r) {
                const int row = rowB + mi * 16 + kh * 4 + r;
                C[(size_t)row * nEd + col] =
                    __builtin_amdgcn_exp2f((acc[mi][ni][r] + bval) * PRESCALE);
            }
        }
    }
    (void)ak; (void)ar;
}

// ---- kMgemmB: fallback with in-loop split (r11-16 proven) ---------------
__global__ __launch_bounds__(256) void kMgemmB(
    const float* __restrict__ A0, const float* __restrict__ A1,
    const unsigned short* __restrict__ WT, const float* __restrict__ bias,
    float* __restrict__ C0, float* __restrict__ C1)
{
    const int z = blockIdx.z;
    const float* __restrict__ A = z ? A1 : A0;
    const unsigned short* __restrict__ Wh = WT + (size_t)z * nEd * nEd;
    const unsigned short* __restrict__ Wl = Wh + (size_t)2 * nEd * nEd;
    float* __restrict__ C = z ? C1 : C0;

    __shared__ unsigned short sAh[32][72];
    __shared__ unsigned short sAl[32][72];
    __shared__ unsigned short sBh[128][72];
    __shared__ unsigned short sBl[128][72];

    const int tid  = threadIdx.x;
    const int lane = tid & 63;
    const int wv   = tid >> 6;
    const int rowB = blockIdx.y * 32;
    const int colB = blockIdx.x * 128;

    const int ar = tid >> 3, ak = (tid & 7) * 8;
    const int br = tid >> 1, bc = (tid & 1) * 32;

    f32x4 acc[2][2] = {};
    const int l15 = lane & 15;
    const int kh  = lane >> 4;

    for (int k0 = 0; k0 < nEd; k0 += 64) {
        const float4 ga0 = *(const float4*)&A[(size_t)(rowB + ar) * nEd + k0 + ak];
        const float4 ga1 = *(const float4*)&A[(size_t)(rowB + ar) * nEd + k0 + ak + 4];
        const size_t wo = (size_t)(colB + br) * nEd + k0 + bc;
        s16x8 gh[4], gl[4];
        #pragma unroll
        for (int j = 0; j < 4; ++j) {
            gh[j] = *(const s16x8*)&Wh[wo + 8 * j];
            gl[j] = *(const s16x8*)&Wl[wo + 8 * j];
        }

        __syncthreads();
        {
            const float a8[8] = {ga0.x, ga0.y, ga0.z, ga0.w,
                                 ga1.x, ga1.y, ga1.z, ga1.w};
            unsigned short h[8], l[8];
            #pragma unroll
            for (int i = 0; i < 8; ++i) {
                h[i] = to_bf(a8[i]);
                l[i] = to_bf(a8[i] - from_bf(h[i]));
            }
            *(ushort4*)&sAh[ar][ak]     = *(ushort4*)&h[0];
            *(ushort4*)&sAh[ar][ak + 4] = *(ushort4*)&h[4];
            *(ushort4*)&sAl[ar][ak]     = *(ushort4*)&l[0];
            *(ushort4*)&sAl[ar][ak + 4] = *(ushort4*)&l[4];
        }
        #pragma unroll
        for (int j = 0; j < 4; ++j) {
            *(s16x8*)&sBh[br][bc + 8 * j] = gh[j];
            *(s16x8*)&sBl[br][bc + 8 * j] = gl[j];
        }
        __syncthreads();

        #pragma unroll
        for (int kk = 0; kk < 2; ++kk) {
            s16x8 fAh[2], fAl[2], fBh[2], fBl[2];
            #pragma unroll
            for (int mi = 0; mi < 2; ++mi) {
                fAh[mi] = *(const s16x8*)&sAh[mi * 16 + l15][kk * 32 + kh * 8];
                fAl[mi] = *(const s16x8*)&sAl[mi * 16 + l15][kk * 32 + kh * 8];
            }
            #pragma unroll
            for (int ni = 0; ni < 2; ++ni) {
                fBh[ni] = *(const s16x8*)&sBh[wv * 32 + ni * 16 + l15][kk * 32 + kh * 8];
                fBl[ni] = *(const s16x8*)&sBl[wv * 32 + ni * 16 + l15][kk * 32 + kh * 8];
            }
            #pragma unroll
            for (int mi = 0; mi < 2; ++mi)
                #pragma unroll
                for (int ni = 0; ni < 2; ++ni) {
                    f32x4 a = acc[mi][ni];
                    a = __builtin_amdgcn_mfma_f32_16x16x32_bf16(fAh[mi], fBh[ni], a, 0, 0, 0);
                    a = __builtin_amdgcn_mfma_f32_16x16x32_bf16(fAl[mi], fBh[ni], a, 0, 0, 0);
                    a = __builtin_amdgcn_mfma_f32_16x16x32_bf16(fAh[mi], fBl[ni], a, 0, 0, 0);
                    acc[mi][ni] = a;
                }
        }
    }

    #pragma unroll
    for (int ni = 0; ni < 2; ++ni) {
        const int col = colB + wv * 32 + ni * 16 + l15;
        const float bval = z ? bias[col] : 0.0f;
        #pragma unroll
        for (int mi = 0; mi < 2; ++mi) {
            #pragma unroll
            for (int r = 0; r < 4; ++r) {
                const int row = rowB + mi * 16 + kh * 4 + r;
                C[(size_t)row * nEd + col] =
                    __builtin_amdgcn_exp2f((acc[mi][ni][r] + bval) * PRESCALE);
            }
        }
    }
}

// ---- kLogSm: pairwise-rcp logits + fused softmax (r16-proven) -----------
__global__ __launch_bounds__(256) void kLogSm(
    const float* __restrict__ X1e,  // [B*S,E] exp2'd
    const float* __restrict__ X2e,  // [B*T,E] exp2'd (bias folded)
    const float* __restrict__ V,    // [E]
    float* __restrict__ attnw)      // [B*T,S] out: softmax weights
{
    const int tg = blockIdx.x, b = blockIdx.y;
    const int tid  = threadIdx.x;
    const int lane = tid & 63;
    const int w    = tid >> 6;
    const int s0 = w * 32;
    const int t0 = tg * 2;

    __shared__ float sm[2][nSq];

    const float4* vp = (const float4*)V;
    float4 n0 = vp[lane * 2], n1 = vp[lane * 2 + 1];
    n0.x *= -2.f; n0.y *= -2.f; n0.z *= -2.f; n0.w *= -2.f;
    n1.x *= -2.f; n1.y *= -2.f; n1.z *= -2.f; n1.w *= -2.f;

    float4 c0[2], c1[2];
    #pragma unroll
    for (int i = 0; i < 2; ++i) {
        const float4* xp = (const float4*)(X2e + ((size_t)b * nTq + t0 + i) * nEd);
        c0[i] = xp[lane * 2];
        c1[i] = xp[lane * 2 + 1];
    }

    const float* X1b = X1e + (size_t)b * nSq * nEd;
    float4 x0 = ((const float4*)(X1b + (size_t)s0 * nEd))[lane * 2];
    float4 x1 = ((const float4*)(X1b + (size_t)s0 * nEd))[lane * 2 + 1];

    #pragma unroll 4
    for (int si = 0; si < 32; ++si) {
        const float4 cx0 = x0, cx1 = x1;
        if (si < 31) {
            const float4* np = (const float4*)(X1b + (size_t)(s0 + si + 1) * nEd);
            x0 = np[lane * 2];
            x1 = np[lane * 2 + 1];
        }
        float a0 = 0.f, a1 = 0.f;
        pair_acc(cx0.x, cx0.y, c0[0].x, c0[0].y, n0.x, n0.y, a0);
        pair_acc(cx0.z, cx0.w, c0[0].z, c0[0].w, n0.z, n0.w, a0);
        pair_acc(cx1.x, cx1.y, c1[0].x, c1[0].y, n1.x, n1.y, a0);
        pair_acc(cx1.z, cx1.w, c1[0].z, c1[0].w, n1.z, n1.w, a0);
        pair_acc(cx0.x, cx0.y, c0[1].x, c0[1].y, n0.x, n0.y, a1);
        pair_acc(cx0.z, cx0.w, c0[1].z, c0[1].w, n0.z, n0.w, a1);
        pair_acc(cx1.x, cx1.y, c1[1].x, c1[1].y, n1.x, n1.y, a1);
        pair_acc(cx1.z, cx1.w, c1[1].z, c1[1].w, n1.z, n1.w, a1);

        const float p0 = a0 + __shfl_xor(a0, 1);
        const float p1 = a1 + __shfl_xor(a1, 1);
        float q = (lane & 1) ? p1 : p0;
        q += __shfl_xor(q, 2);
        q += __shfl_xor(q, 4);
        q += __shfl_xor(q, 8);
        q += __shfl_xor(q, 16);
        q += __shfl_xor(q, 32);
        if (lane < 2) sm[lane][s0 + si] = q;
    }
    __syncthreads();

    if (w < 2) {
        const float l0 = sm[w][lane], l1 = sm[w][lane + 64];
        float m = fmaxf(l0, l1);
        #pragma unroll
        for (int off = 32; off >= 1; off >>= 1)
            m = fmaxf(m, __shfl_xor(m, off));
        const float e0 = __builtin_amdgcn_exp2f((l0 - m) * LOG2E);
        const float e1 = __builtin_amdgcn_exp2f((l1 - m) * LOG2E);
        float sum = e0 + e1;
        #pragma unroll
        for (int off = 32; off >= 1; off >>= 1)
            sum += __shfl_xor(sum, off);
        const float inv = __builtin_amdgcn_rcpf(sum);
        float* ap = attnw + ((size_t)b * nTq + t0 + w) * nSq;
        ap[lane]      = e0 * inv;
        ap[lane + 64] = e1 * inv;
    }
}

// ---- kEncT: standalone fallback (r9-proven) -----------------------------
__global__ __launch_bounds__(256) void kEncT(
    const float* __restrict__ enc, unsigned short* __restrict__ encT)
{
    const int b = blockIdx.z;
    __shared__ float tl[32][33];
    const int r  = threadIdx.x >> 3;
    const int c4 = (threadIdx.x & 7) * 4;
    const int sB = blockIdx.y * 32;
    const int eB = blockIdx.x * 32;
    const float4 v = *(const float4*)&enc[((size_t)b * nSq + sB + r) * nEd + eB + c4];
    tl[r][c4 + 0] = v.x; tl[r][c4 + 1] = v.y;
    tl[r][c4 + 2] = v.z; tl[r][c4 + 3] = v.w;
    __syncthreads();
    unsigned short o[4];
    #pragma unroll
    for (int i = 0; i < 4; ++i) o[i] = to_bf(tl[c4 + i][r]);
    *(ushort4*)&encT[((size_t)b * nEd + eB + r) * nSq + sB + c4] = *(ushort4*)o;
}

// ---- kCtxMM: ctx[b] = bf16(attnw[b]) @ encT[b]^T (r13-proven) -----------
__global__ __launch_bounds__(256) void kCtxMM(
    const float* __restrict__ attnw,          // [B*T,S] f32 weights
    const unsigned short* __restrict__ encT,  // [B*E,S]
    float* __restrict__ ctx)                  // [B*T,E]
{
    const int b  = blockIdx.z;
    const int tB = blockIdx.y * 32;
    const int eB = blockIdx.x * 64;

    __shared__ unsigned short sA[32][136];
    __shared__ unsigned short sB[64][136];

    const int tid  = threadIdx.x;
    const int lane = tid & 63;
    const int w    = tid >> 6;
    const int wm = (w >> 1) * 16;
    const int wn = (w & 1) * 32;
    const int l15 = lane & 15;
    const int kh  = lane >> 4;

    {
        const int r = tid >> 3, c = (tid & 7) * 16;
        const float* ap = &attnw[((size_t)b * nTq + tB + r) * nSq + c];
        unsigned short h[16];
        #pragma unroll
        for (int q = 0; q < 4; ++q) {
            const float4 v = *(const float4*)(ap + 4 * q);
            h[4 * q + 0] = to_bf(v.x); h[4 * q + 1] = to_bf(v.y);
            h[4 * q + 2] = to_bf(v.z); h[4 * q + 3] = to_bf(v.w);
        }
        *(s16x8*)&sA[r][c]     = *(s16x8*)&h[0];
        *(s16x8*)&sA[r][c + 8] = *(s16x8*)&h[8];
    }
    {
        const int r = tid >> 2, c = (tid & 3) * 32;
        const size_t o = ((size_t)b * nEd + eB + r) * nSq + c;
        *(s16x8*)&sB[r][c]      = *(const s16x8*)&encT[o];
        *(s16x8*)&sB[r][c + 8]  = *(const s16x8*)&encT[o + 8];
        *(s16x8*)&sB[r][c + 16] = *(const s16x8*)&encT[o + 16];
        *(s16x8*)&sB[r][c + 24] = *(const s16x8*)&encT[o + 24];
    }
    __syncthreads();

    f32x4 acc[2] = {};
    #pragma unroll
    for (int kk = 0; kk < 4; ++kk) {
        const s16x8 fA = *(const s16x8*)&sA[wm + l15][kk * 32 + kh * 8];
        #pragma unroll
        for (int ni = 0; ni < 2; ++ni) {
            const s16x8 fB = *(const s16x8*)&sB[wn + ni * 16 + l15][kk * 32 + kh * 8];
            acc[ni] = __builtin_amdgcn_mfma_f32_16x16x32_bf16(fA, fB, acc[ni], 0, 0, 0);
        }
    }

    #pragma unroll
    for (int ni = 0; ni < 2; ++ni) {
        const int e = eB + wn + ni * 16 + l15;
        #pragma unroll
        for (int r = 0; r < 4; ++r) {
            const int t = tB + wm + kh * 4 + r;
            ctx[((size_t)b * nTq + t) * nEd + e] = acc[ni][r];
        }
    }
}

extern "C" void kernel_launch(void* const* d_in, const int* in_sizes, int n_in,
                              void* d_out, int out_size, void* d_ws, size_t ws_size,
                              hipStream_t stream) {
    const float* enc = (const float*)d_in[0];   // [16,128,512]
    const float* dec = (const float*)d_in[1];   // [16,128,512]
    const float* W1  = (const float*)d_in[2];   // [512,512]
    const float* W2  = (const float*)d_in[3];   // [512,512]
    const float* bv  = (const float*)d_in[4];   // [512]
    const float* V   = (const float*)d_in[5];   // [512]

    float* ctx   = (float*)d_out;                           // [16,128,512] 4MB
    float* attnw = (float*)d_out + (size_t)nBt * nTq * nEd; // [16,128,128] 1MB

    // WT (hi+lo) in d_out — dead before kCtxMM writes ctx.
    unsigned short* WT = (unsigned short*)d_out;

    const size_t MB = (size_t)1024 * 1024;
    float* ws0 = (float*)d_ws;                    // exp2((enc@W1)*PS), 4MB
    float* ws1 = ws0 + (size_t)nBt * nSq * nEd;   // exp2((dec@W2+b)*PS), 4MB

    const bool early = ws_size >= 18 * MB + 4096;
    unsigned short* encT = early ? (unsigned short*)((char*)d_ws + 8 * MB)
                                 : (unsigned short*)d_ws;

    if (early) {
        unsigned short* Ah = (unsigned short*)((char*)d_ws + 10 * MB);  // 4MB
        unsigned short* Al = (unsigned short*)((char*)d_ws + 14 * MB);  // 4MB
        kPrep<<<dim3(2560), dim3(256), 0, stream>>>(
            W1, W2, WT, enc, dec, encT, Ah, Al);
        kMgemmC<<<dim3(nEd / 128, (nBt * nSq) / 32, 2), dim3(256), 0, stream>>>(
            Ah, Al, WT, bv, ws0, ws1);
        kLogSm<<<dim3(nTq / 2, nBt), dim3(256), 0, stream>>>(ws0, ws1, V, attnw);
    } else {
        kPrep<<<dim3(512), dim3(256), 0, stream>>>(
            W1, W2, WT, enc, dec, nullptr, nullptr, nullptr);
        kMgemmB<<<dim3(nEd / 128, (nBt * nSq) / 32, 2), dim3(256), 0, stream>>>(
            enc, dec, WT, bv, ws0, ws1);
        kLogSm<<<dim3(nTq / 2, nBt), dim3(256), 0, stream>>>(ws0, ws1, V, attnw);
        kEncT<<<dim3(nEd / 32, nSq / 32, nBt), dim3(256), 0, stream>>>(enc, encT);
    }
    kCtxMM<<<dim3(nEd / 64, nTq / 32, nBt), dim3(256), 0, stream>>>(
        attnw, encT, ctx);
}